// Round 4
// baseline (319.873 us; speedup 1.0000x reference)
//
#include <hip/hip_runtime.h>
#include <math.h>

// CapsNet dynamic routing. lane = b (64/block), wave = c-pair (5 waves = 10 caps).
// w loads are wave-uniform but LAUNDERED through an opaque VGPR zero so the compiler
// emits vector loads (deep vmcnt pipelining) instead of SGPR-starved s_load batches.
// No atomics: per-block partials -> ws slab P[ns][b][160]; parallel reduce+squash.
//   x: [512,1152,8] f32, w: [10,1152,16,8] f32, out: [512,10,16] f32

#define BB   512
#define NN1  1152
#define DD1  8
#define CC2  10
#define DD2  16
#define CD   160            // CC2*DD2
#define WCN  (NN1*DD2*DD1)  // 147456 floats per c in w
#define XB   (NN1*DD1)      // 9216 floats per b in x
#define BT   64             // b per block (one per lane)
#define NBC  (BB/BT)        // 8 b-chunks

__device__ __forceinline__ int opaque_zero() {
    int z;
    asm volatile("v_mov_b32 %0, 0" : "=v"(z));
    return z;
}

// ---------------- P1: partial s0 over this block's n-slice ----------------
template<int NS>
__global__ __launch_bounds__(320) void caps_p1(
    const float* __restrict__ x, const float* __restrict__ w, float* __restrict__ P)
{
    constexpr int NT = NN1 / NS;
    const int ns   = blockIdx.x;
    const int bc   = blockIdx.y;
    const int lane = threadIdx.x & 63;
    const int q    = (int)(threadIdx.x >> 6);    // 0..4
    const int c0   = 2 * q;
    const int b    = bc * BT + lane;

    const int z = opaque_zero();                 // forces vector addressing for w
    const float* xp = x + b * XB + ns * NT * DD1;
    const float* p0 = w + c0 * WCN + ns * NT * 128 + z;
    const float* p1 = p0 + WCN;

    float a0[16], a1[16];
#pragma unroll
    for (int d = 0; d < 16; ++d) { a0[d] = 0.f; a1[d] = 0.f; }

#pragma unroll 3
    for (int t = 0; t < NT; ++t) {
        float4 xa = *(const float4*)(xp + t * DD1);
        float4 xb = *(const float4*)(xp + t * DD1 + 4);
#pragma unroll
        for (int d = 0; d < 16; ++d) {
            float4 wa = *(const float4*)(p0 + t * 128 + d * 8);
            float4 wb = *(const float4*)(p0 + t * 128 + d * 8 + 4);
            a0[d] += wa.x*xa.x + wa.y*xa.y + wa.z*xa.z + wa.w*xa.w
                   + wb.x*xb.x + wb.y*xb.y + wb.z*xb.z + wb.w*xb.w;
        }
#pragma unroll
        for (int d = 0; d < 16; ++d) {
            float4 wa = *(const float4*)(p1 + t * 128 + d * 8);
            float4 wb = *(const float4*)(p1 + t * 128 + d * 8 + 4);
            a1[d] += wa.x*xa.x + wa.y*xa.y + wa.z*xa.z + wa.w*xa.w
                   + wb.x*xb.x + wb.y*xb.y + wb.z*xb.z + wb.w*xb.w;
        }
    }

    float* o = P + ((size_t)ns * BB + b) * CD + c0 * DD2;
    *(float4*)(o)      = *(float4*)&a0[0];
    *(float4*)(o + 4)  = *(float4*)&a0[4];
    *(float4*)(o + 8)  = *(float4*)&a0[8];
    *(float4*)(o + 12) = *(float4*)&a0[12];
    *(float4*)(o + 16) = *(float4*)&a1[0];
    *(float4*)(o + 20) = *(float4*)&a1[4];
    *(float4*)(o + 24) = *(float4*)&a1[8];
    *(float4*)(o + 28) = *(float4*)&a1[12];
}

// ------- reduce over ns + squash(alpha*S), element-per-thread, shfl norm -------
__global__ void reduce_squash(const float* __restrict__ P, float* __restrict__ out,
                              int nsplit, float asq)
{
    int t = blockIdx.x * 256 + threadIdx.x;      // element (b,c,d); 16-lane groups = one (b,c)
    if (t >= BB * CD) return;
    float s = 0.f;
    const float* p = P + t;
    for (int ns = 0; ns < nsplit; ++ns, p += (size_t)BB * CD) s += *p;
    float sq = s * s;
#pragma unroll
    for (int m = 1; m < 16; m <<= 1) sq += __shfl_xor(sq, m, 64);   // sum over d
    float qq = asq * sq;                         // |alpha*S|^2
    float sc = qq / (1.f + qq) / sqrtf(sq);      // out = sc * S (alpha folded)
    out[t] = s * sc;
}

// ---------------- P2: logits + softmax + weighted sum; partials to P ----------------
template<int NS>
__global__ __launch_bounds__(320) void caps_p2(
    const float* __restrict__ x, const float* __restrict__ w,
    const float* __restrict__ o0, float* __restrict__ P)
{
    constexpr int NT = NN1 / NS;
    __shared__ float sl[2][CC2][BT];   // logit exchange, double-buffered

    const int ns   = blockIdx.x;
    const int bc   = blockIdx.y;
    const int lane = threadIdx.x & 63;
    const int q    = (int)(threadIdx.x >> 6);
    const int c0   = 2 * q;
    const int b    = bc * BT + lane;

    const int z = opaque_zero();
    const float* xp = x + b * XB + ns * NT * DD1;
    const float* p0 = w + c0 * WCN + ns * NT * 128 + z;
    const float* p1 = p0 + WCN;

    float o0r[2][16];
    {
        const float* p = o0 + b * CD + c0 * DD2;
#pragma unroll
        for (int h = 0; h < 2; ++h) {
            float4 u0 = *(const float4*)(p + h * DD2);
            float4 u1 = *(const float4*)(p + h * DD2 + 4);
            float4 u2 = *(const float4*)(p + h * DD2 + 8);
            float4 u3 = *(const float4*)(p + h * DD2 + 12);
            o0r[h][0]=u0.x;  o0r[h][1]=u0.y;  o0r[h][2]=u0.z;  o0r[h][3]=u0.w;
            o0r[h][4]=u1.x;  o0r[h][5]=u1.y;  o0r[h][6]=u1.z;  o0r[h][7]=u1.w;
            o0r[h][8]=u2.x;  o0r[h][9]=u2.y;  o0r[h][10]=u2.z; o0r[h][11]=u2.w;
            o0r[h][12]=u3.x; o0r[h][13]=u3.y; o0r[h][14]=u3.z; o0r[h][15]=u3.w;
        }
    }

    float s1a[2][16];
#pragma unroll
    for (int d = 0; d < 16; ++d) { s1a[0][d] = 0.f; s1a[1][d] = 0.f; }

#pragma unroll 3
    for (int t = 0; t < NT; ++t) {
        float4 xa = *(const float4*)(xp + t * DD1);
        float4 xb = *(const float4*)(xp + t * DD1 + 4);

        float xh0[16], xh1[16];
#pragma unroll
        for (int d = 0; d < 16; ++d) {
            float4 wa = *(const float4*)(p0 + t * 128 + d * 8);
            float4 wb = *(const float4*)(p0 + t * 128 + d * 8 + 4);
            xh0[d] = wa.x*xa.x + wa.y*xa.y + wa.z*xa.z + wa.w*xa.w
                   + wb.x*xb.x + wb.y*xb.y + wb.z*xb.z + wb.w*xb.w;
        }
#pragma unroll
        for (int d = 0; d < 16; ++d) {
            float4 wa = *(const float4*)(p1 + t * 128 + d * 8);
            float4 wb = *(const float4*)(p1 + t * 128 + d * 8 + 4);
            xh1[d] = wa.x*xa.x + wa.y*xa.y + wa.z*xa.z + wa.w*xa.w
                   + wb.x*xb.x + wb.y*xb.y + wb.z*xb.z + wb.w*xb.w;
        }
        float l0 = 0.f, l1 = 0.f;
#pragma unroll
        for (int d = 0; d < 16; ++d) { l0 += o0r[0][d] * xh0[d]; l1 += o0r[1][d] * xh1[d]; }

        sl[t & 1][c0][lane]     = l0;
        sl[t & 1][c0 + 1][lane] = l1;
        __syncthreads();   // write->read; double buffer keeps next write off this buffer

        float lv[10];
#pragma unroll
        for (int j = 0; j < 10; ++j) lv[j] = sl[t & 1][j][lane];
        float m = lv[0];
#pragma unroll
        for (int j = 1; j < 10; ++j) m = fmaxf(m, lv[j]);
        float den = 0.f;
#pragma unroll
        for (int j = 0; j < 10; ++j) den += __expf(lv[j] - m);
        float inv = 1.f / den;
        float w0 = __expf(lv[c0] - m) * inv;
        float w1 = __expf(lv[c0 + 1] - m) * inv;
#pragma unroll
        for (int d = 0; d < 16; ++d) { s1a[0][d] += w0 * xh0[d]; s1a[1][d] += w1 * xh1[d]; }
    }

    float* o = P + ((size_t)ns * BB + b) * CD + c0 * DD2;
    *(float4*)(o)      = *(float4*)&s1a[0][0];
    *(float4*)(o + 4)  = *(float4*)&s1a[0][4];
    *(float4*)(o + 8)  = *(float4*)&s1a[0][8];
    *(float4*)(o + 12) = *(float4*)&s1a[0][12];
    *(float4*)(o + 16) = *(float4*)&s1a[1][0];
    *(float4*)(o + 20) = *(float4*)&s1a[1][4];
    *(float4*)(o + 24) = *(float4*)&s1a[1][8];
    *(float4*)(o + 28) = *(float4*)&s1a[1][12];
}

extern "C" void kernel_launch(void* const* d_in, const int* in_sizes, int n_in,
                              void* d_out, int out_size, void* d_ws, size_t ws_size,
                              hipStream_t stream)
{
    (void)in_sizes; (void)n_in; (void)out_size;
    const float* x = (const float*)d_in[0];
    const float* w = (const float*)d_in[1];
    float* out = (float*)d_out;
    float* ws  = (float*)d_ws;

#define LAUNCH_NS(NS)                                                              \
    do {                                                                           \
        float* P  = ws;                                                            \
        float* o0 = ws + (size_t)(NS) * BB * CD;                                   \
        caps_p1<NS><<<dim3(NS, NBC), 320, 0, stream>>>(x, w, P);                   \
        reduce_squash<<<(BB*CD + 255)/256, 256, 0, stream>>>(P, o0, NS, 0.01f);    \
        caps_p2<NS><<<dim3(NS, NBC), 320, 0, stream>>>(x, w, o0, P);               \
        reduce_squash<<<(BB*CD + 255)/256, 256, 0, stream>>>(P, out, NS, 1.0f);    \
    } while (0)

    const size_t slab = (size_t)BB * CD * sizeof(float);   // 327680 B
    if      (ws_size >= slab * 129) LAUNCH_NS(128);
    else if (ws_size >= slab * 65)  LAUNCH_NS(64);
    else if (ws_size >= slab * 33)  LAUNCH_NS(32);
    else if (ws_size >= slab * 9)   LAUNCH_NS(8);
    else                            LAUNCH_NS(1);
#undef LAUNCH_NS
}